// Round 3
// baseline (3654.780 us; speedup 1.0000x reference)
//
#include <hip/hip_runtime.h>
#include <hip/hip_bf16.h>
#include <math.h>
#include <float.h>

// Problem dims
#define BDIM   64
#define PDIM   196
#define ENC    2048
#define DECD   512
#define ATTD   512
#define EMBD   512
#define VOC    10000
#define LCAP   30
#define TSTEPS 29

typedef __attribute__((ext_vector_type(8))) short s8v;   // 8 x bf16
typedef __attribute__((ext_vector_type(4))) float f4v;   // MFMA acc

__device__ __forceinline__ float sigf(float x) { return 1.0f / (1.0f + expf(-x)); }
__device__ __forceinline__ float bf2f(ushort u) { return __uint_as_float(((uint)u) << 16); }

// ---------------------------------------------------------------------------
// stable sort by length desc (ties by index asc)
// ---------------------------------------------------------------------------
__global__ void sort_kernel(const int* __restrict__ cap_len,
                            const int* __restrict__ caps,
                            int* __restrict__ sort_ind,
                            int* __restrict__ dec_lens,
                            int* __restrict__ caps_s,
                            float* __restrict__ out_caps,
                            float* __restrict__ out_dlen,
                            float* __restrict__ out_sind) {
    int i = threadIdx.x;  // 64 threads
    __shared__ int len[BDIM];
    len[i] = cap_len[i];
    __syncthreads();
    int li = len[i];
    int r = 0;
    for (int j = 0; j < BDIM; ++j) {
        int lj = len[j];
        if (lj > li || (lj == li && j < i)) ++r;
    }
    sort_ind[r] = i;
    dec_lens[r] = li - 1;
    out_sind[r] = (float)i;
    out_dlen[r] = (float)(li - 1);
    for (int tt = 0; tt < LCAP; ++tt) {
        int v = caps[i * LCAP + tt];
        caps_s[r * LCAP + tt] = v;
        out_caps[r * LCAP + tt] = (float)v;
    }
}

// ---------------------------------------------------------------------------
// Gather-sort enc -> bf16 enc_s, and compute mean_enc (fp32) in one pass.
// ---------------------------------------------------------------------------
__global__ __launch_bounds__(256) void conv_enc_kernel(const float* __restrict__ enc,
                                                       const int* __restrict__ sort_ind,
                                                       __hip_bfloat16* __restrict__ enc_s,
                                                       float* __restrict__ mean_enc) {
    int b = blockIdx.y, tid = threadIdx.x;
    int e = (blockIdx.x << 8) + tid;
    const float* ep = enc + (size_t)sort_ind[b] * (PDIM * ENC) + e;
    __hip_bfloat16* op = enc_s + (size_t)b * (PDIM * ENC) + e;
    float s = 0.f;
    for (int p = 0; p < PDIM; ++p) {
        float v = ep[(size_t)p * ENC];
        s += v;
        op[(size_t)p * ENC] = __float2bfloat16(v);
    }
    mean_enc[(size_t)b * ENC + e] = s * (1.0f / (float)PDIM);
}

// generic fp32 -> bf16
__global__ __launch_bounds__(256) void f2b_kernel(const float* __restrict__ src,
                                                  __hip_bfloat16* __restrict__ dst, int n) {
    int i = blockIdx.x * 256 + threadIdx.x;
    if (i < n) dst[i] = __float2bfloat16(src[i]);
}

// h0 fp32 -> xh bf16 h-slot
__global__ __launch_bounds__(256) void h0_kernel(const float* __restrict__ h0f,
                                                 __hip_bfloat16* __restrict__ xh) {
    int idx = blockIdx.x * 256 + threadIdx.x;  // < 64*512
    int b = idx >> 9, j = idx & 511;
    xh[(size_t)b * 3072 + 2560 + j] = __float2bfloat16(h0f[idx]);
}

// ---------------------------------------------------------------------------
// fp32 tiled GEMM (tiny h0/c0 inits only): C = A@W^T + bias, M=64
// ---------------------------------------------------------------------------
__global__ __launch_bounds__(256) void gemm32_k(
    const float* __restrict__ A, int lda,
    const float* __restrict__ W0, const float* __restrict__ bias0,
    float* __restrict__ C, int ldc, int K) {
    __shared__ float As[16][64];
    __shared__ float Ws[16][64];
    const int tid = threadIdx.x;
    const int tx = tid & 15, ty = tid >> 4;
    const int bn0 = blockIdx.x * 64;
    const int lr = tid >> 2;
    const int lk = (tid & 3) << 2;
    const float* Arow = A + (size_t)lr * lda;
    const int wn = bn0 + lr;
    float acc[4][4];
#pragma unroll
    for (int i = 0; i < 4; ++i)
#pragma unroll
        for (int j = 0; j < 4; ++j) acc[i][j] = 0.f;
    for (int k0 = 0; k0 < K; k0 += 16) {
        float4 av = *(const float4*)(Arow + k0 + lk);
        float4 wv = *(const float4*)(W0 + (size_t)wn * K + k0 + lk);
        __syncthreads();
        As[lk + 0][lr] = av.x; As[lk + 1][lr] = av.y;
        As[lk + 2][lr] = av.z; As[lk + 3][lr] = av.w;
        Ws[lk + 0][lr] = wv.x; Ws[lk + 1][lr] = wv.y;
        Ws[lk + 2][lr] = wv.z; Ws[lk + 3][lr] = wv.w;
        __syncthreads();
#pragma unroll
        for (int kk = 0; kk < 16; ++kk) {
            const float4 a = *(const float4*)&As[kk][ty << 2];
            const float4 w = *(const float4*)&Ws[kk][tx << 2];
            acc[0][0] += a.x * w.x; acc[0][1] += a.x * w.y; acc[0][2] += a.x * w.z; acc[0][3] += a.x * w.w;
            acc[1][0] += a.y * w.x; acc[1][1] += a.y * w.y; acc[1][2] += a.y * w.z; acc[1][3] += a.y * w.w;
            acc[2][0] += a.z * w.x; acc[2][1] += a.z * w.y; acc[2][2] += a.z * w.z; acc[2][3] += a.z * w.w;
            acc[3][0] += a.w * w.x; acc[3][1] += a.w * w.y; acc[3][2] += a.w * w.z; acc[3][3] += a.w * w.w;
        }
    }
#pragma unroll
    for (int i = 0; i < 4; ++i) {
        int row = (ty << 2) + i;
#pragma unroll
        for (int j = 0; j < 4; ++j) {
            int col = bn0 + (tx << 2) + j;
            C[(size_t)row * ldc + col] = acc[i][j] + bias0[col];
        }
    }
}

// ---------------------------------------------------------------------------
// MFMA bf16 GEMM, 1 wave/block, (16*MF) x 64 tile of C = A@W^T.
// Compile-time K (KA on W0, optional KB tail on W1 for GM_GATES).
// XM=true puts the m-tile on blockIdx.x (XCD co-location of same-m blocks).
// Modes: E_ATT1 (bf16 out), E_GACT (sigmoid|plain fp32 out, n-split 2048),
//        E_GATES (fp32 out, k-split KA), E_PREDS (masked strided fp32 out).
// ---------------------------------------------------------------------------
enum { E_ATT1 = 0, E_GACT = 1, E_GATES = 2, E_PREDS = 3 };

template <int MF, int MODE, int KA, int KB, bool XM>
__global__ __launch_bounds__(64) void mfma_gemm(
    const __hip_bfloat16* __restrict__ A, int lda,
    const __hip_bfloat16* __restrict__ W0, const __hip_bfloat16* __restrict__ W1,
    const float* __restrict__ bias0, const float* __restrict__ bias1,
    void* __restrict__ Cv,
    const int* __restrict__ dec_lens, int t) {
    const int l = threadIdx.x;
    const int c16 = l & 15, kg = l >> 4;
    const int n0 = (XM ? (int)blockIdx.y : (int)blockIdx.x) * 64;
    const int m0 = (XM ? (int)blockIdx.x : (int)blockIdx.y) * (16 * MF);

    f4v acc[MF][4];
#pragma unroll
    for (int mi = 0; mi < MF; ++mi)
#pragma unroll
        for (int ni = 0; ni < 4; ++ni) acc[mi][ni] = (f4v)0.0f;

    const __hip_bfloat16* arow[MF];
#pragma unroll
    for (int mi = 0; mi < MF; ++mi)
        arow[mi] = A + (size_t)(m0 + mi * 16 + c16) * lda + kg * 8;

    const __hip_bfloat16* w0r[4];
    const __hip_bfloat16* w1r[4];
#pragma unroll
    for (int ni = 0; ni < 4; ++ni) {
        int n = n0 + ni * 16 + c16;
        if (MODE == E_GACT) {
            w0r[ni] = (n < 2048) ? W0 + (size_t)n * 512 : W1 + (size_t)(n - 2048) * 512;
        } else if (MODE == E_GATES) {
            w0r[ni] = W0 + (size_t)n * (KA);        // W_ih rows, stride KA=2560
            w1r[ni] = W1 + (size_t)n * (KB);        // W_hh rows, stride KB=512
        } else if (MODE == E_PREDS) {
            int nn = (n < VOC) ? n : (VOC - 1);
            w0r[ni] = W0 + (size_t)nn * KA;
        } else {                                     // E_ATT1
            w0r[ni] = W0 + (size_t)n * KA;
        }
        w0r[ni] += kg * 8;
        if (MODE == E_GATES) w1r[ni] += kg * 8;
    }

#pragma unroll 8
    for (int k0 = 0; k0 < KA; k0 += 32) {
        s8v a[MF], b[4];
#pragma unroll
        for (int mi = 0; mi < MF; ++mi) a[mi] = *(const s8v*)(arow[mi] + k0);
#pragma unroll
        for (int ni = 0; ni < 4; ++ni) b[ni] = *(const s8v*)(w0r[ni] + k0);
#pragma unroll
        for (int mi = 0; mi < MF; ++mi)
#pragma unroll
            for (int ni = 0; ni < 4; ++ni)
                acc[mi][ni] = __builtin_amdgcn_mfma_f32_16x16x32_bf16(a[mi], b[ni], acc[mi][ni], 0, 0, 0);
    }
    if constexpr (KB > 0) {
#pragma unroll
        for (int k0 = 0; k0 < KB; k0 += 32) {
            s8v a[MF], b[4];
#pragma unroll
            for (int mi = 0; mi < MF; ++mi) a[mi] = *(const s8v*)(arow[mi] + KA + k0);
#pragma unroll
            for (int ni = 0; ni < 4; ++ni) b[ni] = *(const s8v*)(w1r[ni] + k0);
#pragma unroll
            for (int mi = 0; mi < MF; ++mi)
#pragma unroll
                for (int ni = 0; ni < 4; ++ni)
                    acc[mi][ni] = __builtin_amdgcn_mfma_f32_16x16x32_bf16(a[mi], b[ni], acc[mi][ni], 0, 0, 0);
        }
    }

#pragma unroll
    for (int mi = 0; mi < MF; ++mi) {
#pragma unroll
        for (int ni = 0; ni < 4; ++ni) {
#pragma unroll
            for (int i = 0; i < 4; ++i) {
                int r = m0 + mi * 16 + kg * 4 + i;
                int c = n0 + ni * 16 + c16;
                float v = acc[mi][ni][i];
                if (MODE == E_ATT1) {
                    ((__hip_bfloat16*)Cv)[(size_t)r * 512 + c] = __float2bfloat16(v + bias0[c]);
                } else if (MODE == E_GACT) {
                    float* C = (float*)Cv;
                    if (c < 2048) C[(size_t)r * 2560 + c] = sigf(v + bias0[c]);
                    else          C[(size_t)r * 2560 + c] = v + bias1[c - 2048];
                } else if (MODE == E_GATES) {
                    ((float*)Cv)[(size_t)r * 2048 + c] = v + bias0[c] + bias1[c];
                } else {  // E_PREDS
                    if (c < VOC) {
                        float o = v + bias0[c];
                        ((float*)Cv)[(size_t)r * (TSTEPS * VOC) + (size_t)t * VOC + c] =
                            (t < dec_lens[r]) ? o : 0.f;
                    }
                }
            }
        }
    }
}

// ---------------------------------------------------------------------------
// Fused attention: e-scores -> softmax -> awe (gated) + emb gather into xh.
// One block per b, 256 threads. alpha never leaves LDS (except out_alphas).
// ---------------------------------------------------------------------------
__global__ __launch_bounds__(256) void attawe_kernel(
    const __hip_bfloat16* __restrict__ att1, const float* __restrict__ gact,
    const __hip_bfloat16* __restrict__ enc_s,
    const float* __restrict__ w_full, const float* __restrict__ b_full,
    const float* __restrict__ emb_table,
    const int* __restrict__ caps_s, const int* __restrict__ dec_lens,
    __hip_bfloat16* __restrict__ xh, float* __restrict__ out_alphas, int t) {
    int b = blockIdx.x;
    int tid = threadIdx.x;
    __shared__ float s_att2[ATTD];
    __shared__ float s_wf[ATTD];
    __shared__ float s_e[PDIM];
    __shared__ float red[256];

    s_att2[tid]       = gact[(size_t)b * 2560 + 2048 + tid];
    s_att2[tid + 256] = gact[(size_t)b * 2560 + 2048 + 256 + tid];
    s_wf[tid]       = w_full[tid];
    s_wf[tid + 256] = w_full[tid + 256];
    __syncthreads();

    // --- e-scores ---
    int wv = tid >> 6, lane = tid & 63;
    const float bf = b_full[0];
    const int a0 = lane << 3;
    for (int p = wv; p < PDIM; p += 4) {
        const ushort* row = (const ushort*)att1 + ((size_t)b * PDIM + p) * ATTD + a0;
        float s = 0.f;
#pragma unroll
        for (int i = 0; i < 8; ++i) {
            float x = bf2f(row[i]) + s_att2[a0 + i];
            s += fmaxf(x, 0.f) * s_wf[a0 + i];
        }
#pragma unroll
        for (int off = 32; off; off >>= 1) s += __shfl_xor(s, off);
        if (lane == 0) s_e[p] = s + bf;
    }
    __syncthreads();

    // --- softmax (alpha stays in s_e) ---
    float v = (tid < PDIM) ? s_e[tid] : -FLT_MAX;
    red[tid] = v;
    __syncthreads();
    for (int st = 128; st; st >>= 1) {
        if (tid < st) red[tid] = fmaxf(red[tid], red[tid + st]);
        __syncthreads();
    }
    float mx = red[0];
    __syncthreads();
    float ex = (tid < PDIM) ? expf(v - mx) : 0.f;
    red[tid] = ex;
    __syncthreads();
    for (int st = 128; st; st >>= 1) {
        if (tid < st) red[tid] += red[tid + st];
        __syncthreads();
    }
    float inv = 1.f / red[0];
    __syncthreads();
    if (tid < PDIM) {
        float al = ex * inv;
        s_e[tid] = al;
        out_alphas[(size_t)b * (TSTEPS * PDIM) + (size_t)t * PDIM + tid] =
            (t < dec_lens[b]) ? al : 0.f;
    }
    __syncthreads();

    // --- awe: thread owns 8 consecutive e's (16B bf16 loads) ---
    int e = tid << 3;
    const ushort* ep = (const ushort*)enc_s + (size_t)b * (PDIM * ENC) + e;
    float acc[8];
#pragma unroll
    for (int i = 0; i < 8; ++i) acc[i] = 0.f;
#pragma unroll 2
    for (int p = 0; p < PDIM; ++p) {
        float al = s_e[p];
        s8v u = *(const s8v*)(ep + (size_t)p * ENC);
#pragma unroll
        for (int i = 0; i < 8; ++i) acc[i] += al * bf2f((ushort)u[i]);
    }
    float4 g0 = *(const float4*)(gact + (size_t)b * 2560 + e);
    float4 g1 = *(const float4*)(gact + (size_t)b * 2560 + e + 4);
    __hip_bfloat16 ob[8];
    ob[0] = __float2bfloat16(acc[0] * g0.x); ob[1] = __float2bfloat16(acc[1] * g0.y);
    ob[2] = __float2bfloat16(acc[2] * g0.z); ob[3] = __float2bfloat16(acc[3] * g0.w);
    ob[4] = __float2bfloat16(acc[4] * g1.x); ob[5] = __float2bfloat16(acc[5] * g1.y);
    ob[6] = __float2bfloat16(acc[6] * g1.z); ob[7] = __float2bfloat16(acc[7] * g1.w);
    *(uint4*)(xh + (size_t)b * 3072 + 512 + e) = *(uint4*)ob;

    // --- embedding gather ---
    if (tid < 128) {
        int cap = caps_s[b * LCAP + t];
        int j = tid << 2;
        float4 em = *(const float4*)(emb_table + (size_t)cap * EMBD + j);
        __hip_bfloat16 eb[4];
        eb[0] = __float2bfloat16(em.x); eb[1] = __float2bfloat16(em.y);
        eb[2] = __float2bfloat16(em.z); eb[3] = __float2bfloat16(em.w);
        *(uint2*)(xh + (size_t)b * 3072 + j) = *(uint2*)eb;
    }
}

// ---------------------------------------------------------------------------
// LSTM cell: update c (fp32), write h (bf16) into xh.
// ---------------------------------------------------------------------------
__global__ __launch_bounds__(256) void cell_kernel(const float* __restrict__ gates,
                                                   float* __restrict__ c,
                                                   __hip_bfloat16* __restrict__ xh) {
    int idx = blockIdx.x * 256 + threadIdx.x;  // < 64*512
    int b = idx >> 9, j = idx & 511;
    const float* g = gates + (size_t)b * 2048;
    float i_ = sigf(g[j]);
    float f_ = sigf(g[512 + j]);
    float g_ = tanhf(g[1024 + j]);
    float o_ = sigf(g[1536 + j]);
    float cn = f_ * c[idx] + i_ * g_;
    c[idx] = cn;
    xh[(size_t)b * 3072 + 2560 + j] = __float2bfloat16(o_ * tanhf(cn));
}

// ---------------------------------------------------------------------------
extern "C" void kernel_launch(void* const* d_in, const int* in_sizes, int n_in,
                              void* d_out, int out_size, void* d_ws, size_t ws_size,
                              hipStream_t stream) {
    const float* enc      = (const float*)d_in[0];
    const int*   caps     = (const int*)d_in[1];
    const int*   clen     = (const int*)d_in[2];
    const float* W_enc    = (const float*)d_in[3];
    const float* b_enc    = (const float*)d_in[4];
    const float* W_dec    = (const float*)d_in[5];
    const float* b_dec    = (const float*)d_in[6];
    const float* w_full   = (const float*)d_in[7];
    const float* b_full   = (const float*)d_in[8];
    const float* emb_tab  = (const float*)d_in[9];
    const float* W_ih     = (const float*)d_in[10];
    const float* b_ih     = (const float*)d_in[11];
    const float* W_hh     = (const float*)d_in[12];
    const float* b_hh     = (const float*)d_in[13];
    const float* W_init_h = (const float*)d_in[14];
    const float* b_init_h = (const float*)d_in[15];
    const float* W_init_c = (const float*)d_in[16];
    const float* b_init_c = (const float*)d_in[17];
    const float* W_beta   = (const float*)d_in[18];
    const float* b_beta   = (const float*)d_in[19];
    const float* W_fc     = (const float*)d_in[20];
    const float* b_fc     = (const float*)d_in[21];

    float* out_pred = (float*)d_out;
    float* out_alph = out_pred + (size_t)BDIM * TSTEPS * VOC;
    float* out_caps = out_alph + (size_t)BDIM * TSTEPS * PDIM;
    float* out_dlen = out_caps + BDIM * LCAP;
    float* out_sind = out_dlen + BDIM;

    // ---- workspace carve-up (256B aligned) ----
    char* p = (char*)d_ws;
    auto carve = [&](size_t bytes) { char* r = p; p += (bytes + 255) & ~(size_t)255; return r; };
    int* sort_ind = (int*)carve(64 * 4);
    int* dec_lens = (int*)carve(64 * 4);
    int* caps_s   = (int*)carve(64 * LCAP * 4);
    float* mean_e = (float*)carve((size_t)64 * ENC * 4);
    float* h0f    = (float*)carve((size_t)64 * 512 * 4);
    float* cbuf   = (float*)carve((size_t)64 * 512 * 4);
    float* gact   = (float*)carve((size_t)64 * 2560 * 4);
    float* gates  = (float*)carve((size_t)64 * 2048 * 4);
    __hip_bfloat16* xh     = (__hip_bfloat16*)carve((size_t)64 * 3072 * 2);
    __hip_bfloat16* enc_s  = (__hip_bfloat16*)carve((size_t)64 * PDIM * ENC * 2);
    __hip_bfloat16* att1   = (__hip_bfloat16*)carve((size_t)64 * PDIM * 512 * 2);
    __hip_bfloat16* Wb_enc = (__hip_bfloat16*)carve((size_t)512 * 2048 * 2);
    __hip_bfloat16* Wb_bet = (__hip_bfloat16*)carve((size_t)2048 * 512 * 2);
    __hip_bfloat16* Wb_dec = (__hip_bfloat16*)carve((size_t)512 * 512 * 2);
    __hip_bfloat16* Wb_ih  = (__hip_bfloat16*)carve((size_t)2048 * 2560 * 2);
    __hip_bfloat16* Wb_hh  = (__hip_bfloat16*)carve((size_t)2048 * 512 * 2);
    __hip_bfloat16* Wb_fc  = (__hip_bfloat16*)carve((size_t)VOC * 512 * 2);

    // ---- init phase ----
    sort_kernel<<<1, 64, 0, stream>>>(clen, caps, sort_ind, dec_lens, caps_s,
                                      out_caps, out_dlen, out_sind);
    conv_enc_kernel<<<dim3(8, 64), 256, 0, stream>>>(enc, sort_ind, enc_s, mean_e);
    f2b_kernel<<<(512 * 2048 + 255) / 256, 256, 0, stream>>>(W_enc, Wb_enc, 512 * 2048);
    f2b_kernel<<<(2048 * 512 + 255) / 256, 256, 0, stream>>>(W_beta, Wb_bet, 2048 * 512);
    f2b_kernel<<<(512 * 512 + 255) / 256, 256, 0, stream>>>(W_dec, Wb_dec, 512 * 512);
    f2b_kernel<<<(2048 * 2560 + 255) / 256, 256, 0, stream>>>(W_ih, Wb_ih, 2048 * 2560);
    f2b_kernel<<<(2048 * 512 + 255) / 256, 256, 0, stream>>>(W_hh, Wb_hh, 2048 * 512);
    f2b_kernel<<<(VOC * 512 + 255) / 256, 256, 0, stream>>>(W_fc, Wb_fc, VOC * 512);

    gemm32_k<<<dim3(8, 1), 256, 0, stream>>>(mean_e, ENC, W_init_h, b_init_h, h0f, 512, ENC);
    gemm32_k<<<dim3(8, 1), 256, 0, stream>>>(mean_e, ENC, W_init_c, b_init_c, cbuf, 512, ENC);
    h0_kernel<<<128, 256, 0, stream>>>(h0f, xh);

    // att1 = enc_s @ W_enc^T + b_enc  (M=12544, N=512, K=2048) -> bf16
    // grid.x = m-tiles (392 ≡ 0 mod 8): all 8 n-blocks of an m-tile share an XCD.
    mfma_gemm<2, E_ATT1, 2048, 0, true><<<dim3(392, 8), 64, 0, stream>>>(
        enc_s, ENC, Wb_enc, nullptr, b_enc, nullptr, att1, nullptr, 0);

    // ---- decode loop ----
    for (int t = 0; t < TSTEPS; ++t) {
        // gate=sigmoid(h@W_beta^T+b_beta) | att2=h@W_dec^T+b_dec  (N=2560, K=512)
        mfma_gemm<1, E_GACT, 512, 0, false><<<dim3(40, 4), 64, 0, stream>>>(
            xh + 2560, 3072, Wb_bet, Wb_dec, b_beta, b_dec, gact, nullptr, 0);
        // fused e-scores + softmax + gated awe + emb gather
        attawe_kernel<<<64, 256, 0, stream>>>(att1, gact, enc_s, w_full, b_full,
                                              emb_tab, caps_s, dec_lens, xh,
                                              out_alph, t);
        // gates = x@W_ih^T + h@W_hh^T + b_ih + b_hh  (N=2048, K=2560+512)
        mfma_gemm<1, E_GATES, 2560, 512, false><<<dim3(32, 4), 64, 0, stream>>>(
            xh, 3072, Wb_ih, Wb_hh, b_ih, b_hh, gates, nullptr, 0);
        cell_kernel<<<128, 256, 0, stream>>>(gates, cbuf, xh);
        // preds = h_new@W_fc^T + b_fc  (N=10000, K=512), masked strided store
        // grid.x padded 157->160 so weight-sharing groups co-locate per XCD.
        mfma_gemm<1, E_PREDS, 512, 0, false><<<dim3(160, 4), 64, 0, stream>>>(
            xh + 2560, 3072, Wb_fc, nullptr, b_fc, nullptr, out_pred, dec_lens, t);
    }
}

// Round 5
// 3251.196 us; speedup vs baseline: 1.1241x; 1.1241x over previous
//
#include <hip/hip_runtime.h>
#include <hip/hip_bf16.h>
#include <math.h>
#include <float.h>

// Problem dims
#define BDIM   64
#define PDIM   196
#define ENC    2048
#define DECD   512
#define ATTD   512
#define EMBD   512
#define VOC    10000
#define LCAP   30
#define TSTEPS 29

typedef __attribute__((ext_vector_type(8))) short s8v;   // 8 x bf16
typedef __attribute__((ext_vector_type(4))) float f4v;   // MFMA acc

__device__ __forceinline__ float sigf(float x) { return 1.0f / (1.0f + expf(-x)); }
__device__ __forceinline__ float bf2f(ushort u) { return __uint_as_float(((uint)u) << 16); }

// ---------------------------------------------------------------------------
// Pipelined MFMA K-segment: NIT iterations of k+=32, 3-slot register rotation,
// prefetch distance 2. All indices compile-time after full unroll.
// ---------------------------------------------------------------------------
template <int MF, int NIT>
__device__ __forceinline__ void gemm_seg(const __hip_bfloat16* const* arow,
                                         const __hip_bfloat16* const* wrow,
                                         f4v acc[][4]) {
    s8v aP[3][MF], bP[3][4];
    auto LD = [&](int it, int slot) {
#pragma unroll
        for (int mi = 0; mi < MF; ++mi) aP[slot][mi] = *(const s8v*)(arow[mi] + it * 32);
#pragma unroll
        for (int ni = 0; ni < 4; ++ni)  bP[slot][ni] = *(const s8v*)(wrow[ni] + it * 32);
    };
    LD(0, 0);
    if constexpr (NIT > 1) LD(1, 1);
#pragma unroll
    for (int it = 0; it < NIT; ++it) {
        if (it + 2 < NIT) LD(it + 2, (it + 2) % 3);
        const int s = it % 3;
#pragma unroll
        for (int mi = 0; mi < MF; ++mi)
#pragma unroll
            for (int ni = 0; ni < 4; ++ni)
                acc[mi][ni] = __builtin_amdgcn_mfma_f32_16x16x32_bf16(aP[s][mi], bP[s][ni], acc[mi][ni], 0, 0, 0);
    }
}

// ---------------------------------------------------------------------------
// stable sort by length desc (ties by index asc)
// ---------------------------------------------------------------------------
__global__ void sort_kernel(const int* __restrict__ cap_len,
                            const int* __restrict__ caps,
                            int* __restrict__ sort_ind,
                            int* __restrict__ dec_lens,
                            int* __restrict__ caps_s,
                            float* __restrict__ out_caps,
                            float* __restrict__ out_dlen,
                            float* __restrict__ out_sind) {
    int i = threadIdx.x;  // 64 threads
    __shared__ int len[BDIM];
    len[i] = cap_len[i];
    __syncthreads();
    int li = len[i];
    int r = 0;
    for (int j = 0; j < BDIM; ++j) {
        int lj = len[j];
        if (lj > li || (lj == li && j < i)) ++r;
    }
    sort_ind[r] = i;
    dec_lens[r] = li - 1;
    out_sind[r] = (float)i;
    out_dlen[r] = (float)(li - 1);
    for (int tt = 0; tt < LCAP; ++tt) {
        int v = caps[i * LCAP + tt];
        caps_s[r * LCAP + tt] = v;
        out_caps[r * LCAP + tt] = (float)v;
    }
}

// ---------------------------------------------------------------------------
// Gather-sort enc -> bf16 enc_s, and compute mean_enc (fp32) in one pass.
// ---------------------------------------------------------------------------
__global__ __launch_bounds__(256) void conv_enc_kernel(const float* __restrict__ enc,
                                                       const int* __restrict__ sort_ind,
                                                       __hip_bfloat16* __restrict__ enc_s,
                                                       float* __restrict__ mean_enc) {
    int b = blockIdx.y, tid = threadIdx.x;
    int e = (blockIdx.x << 8) + tid;
    const float* ep = enc + (size_t)sort_ind[b] * (PDIM * ENC) + e;
    __hip_bfloat16* op = enc_s + (size_t)b * (PDIM * ENC) + e;
    float s = 0.f;
    for (int p = 0; p < PDIM; ++p) {
        float v = ep[(size_t)p * ENC];
        s += v;
        op[(size_t)p * ENC] = __float2bfloat16(v);
    }
    mean_enc[(size_t)b * ENC + e] = s * (1.0f / (float)PDIM);
}

// generic fp32 -> bf16
__global__ __launch_bounds__(256) void f2b_kernel(const float* __restrict__ src,
                                                  __hip_bfloat16* __restrict__ dst, int n) {
    int i = blockIdx.x * 256 + threadIdx.x;
    if (i < n) dst[i] = __float2bfloat16(src[i]);
}

// h0 fp32 -> xh bf16 h-slot
__global__ __launch_bounds__(256) void h0_kernel(const float* __restrict__ h0f,
                                                 __hip_bfloat16* __restrict__ xh) {
    int idx = blockIdx.x * 256 + threadIdx.x;  // < 64*512
    int b = idx >> 9, j = idx & 511;
    xh[(size_t)b * 3072 + 2560 + j] = __float2bfloat16(h0f[idx]);
}

// ---------------------------------------------------------------------------
// fp32 tiled GEMM (tiny h0/c0 inits only): C = A@W^T + bias, M=64
// ---------------------------------------------------------------------------
__global__ __launch_bounds__(256) void gemm32_k(
    const float* __restrict__ A, int lda,
    const float* __restrict__ W0, const float* __restrict__ bias0,
    float* __restrict__ C, int ldc, int K) {
    __shared__ float As[16][64];
    __shared__ float Ws[16][64];
    const int tid = threadIdx.x;
    const int tx = tid & 15, ty = tid >> 4;
    const int bn0 = blockIdx.x * 64;
    const int lr = tid >> 2;
    const int lk = (tid & 3) << 2;
    const float* Arow = A + (size_t)lr * lda;
    const int wn = bn0 + lr;
    float acc[4][4];
#pragma unroll
    for (int i = 0; i < 4; ++i)
#pragma unroll
        for (int j = 0; j < 4; ++j) acc[i][j] = 0.f;
    for (int k0 = 0; k0 < K; k0 += 16) {
        float4 av = *(const float4*)(Arow + k0 + lk);
        float4 wv = *(const float4*)(W0 + (size_t)wn * K + k0 + lk);
        __syncthreads();
        As[lk + 0][lr] = av.x; As[lk + 1][lr] = av.y;
        As[lk + 2][lr] = av.z; As[lk + 3][lr] = av.w;
        Ws[lk + 0][lr] = wv.x; Ws[lk + 1][lr] = wv.y;
        Ws[lk + 2][lr] = wv.z; Ws[lk + 3][lr] = wv.w;
        __syncthreads();
#pragma unroll
        for (int kk = 0; kk < 16; ++kk) {
            const float4 a = *(const float4*)&As[kk][ty << 2];
            const float4 w = *(const float4*)&Ws[kk][tx << 2];
            acc[0][0] += a.x * w.x; acc[0][1] += a.x * w.y; acc[0][2] += a.x * w.z; acc[0][3] += a.x * w.w;
            acc[1][0] += a.y * w.x; acc[1][1] += a.y * w.y; acc[1][2] += a.y * w.z; acc[1][3] += a.y * w.w;
            acc[2][0] += a.z * w.x; acc[2][1] += a.z * w.y; acc[2][2] += a.z * w.z; acc[2][3] += a.z * w.w;
            acc[3][0] += a.w * w.x; acc[3][1] += a.w * w.y; acc[3][2] += a.w * w.z; acc[3][3] += a.w * w.w;
        }
    }
#pragma unroll
    for (int i = 0; i < 4; ++i) {
        int row = (ty << 2) + i;
#pragma unroll
        for (int j = 0; j < 4; ++j) {
            int col = bn0 + (tx << 2) + j;
            C[(size_t)row * ldc + col] = acc[i][j] + bias0[col];
        }
    }
}

// ---------------------------------------------------------------------------
// att1 = enc_s @ W_enc^T + b_enc  -> bf16.  MF=2, K=2048.
// grid (392 m-tiles, 8 n-tiles): same-m blocks co-locate per XCD.
// ---------------------------------------------------------------------------
__global__ __launch_bounds__(64) void att1_gemm(
    const __hip_bfloat16* __restrict__ A, const __hip_bfloat16* __restrict__ W,
    const float* __restrict__ bias, __hip_bfloat16* __restrict__ C) {
    const int l = threadIdx.x, c16 = l & 15, kg = l >> 4;
    const int m0 = blockIdx.x * 32, n0 = blockIdx.y * 64;
    f4v acc[2][4];
#pragma unroll
    for (int mi = 0; mi < 2; ++mi)
#pragma unroll
        for (int ni = 0; ni < 4; ++ni) acc[mi][ni] = (f4v)0.0f;
    const __hip_bfloat16* arow[2];
#pragma unroll
    for (int mi = 0; mi < 2; ++mi)
        arow[mi] = A + (size_t)(m0 + mi * 16 + c16) * ENC + kg * 8;
    const __hip_bfloat16* wrow[4];
#pragma unroll
    for (int ni = 0; ni < 4; ++ni)
        wrow[ni] = W + (size_t)(n0 + ni * 16 + c16) * ENC + kg * 8;
    gemm_seg<2, 64>(arow, wrow, acc);
#pragma unroll
    for (int mi = 0; mi < 2; ++mi)
#pragma unroll
        for (int ni = 0; ni < 4; ++ni)
#pragma unroll
            for (int i = 0; i < 4; ++i) {
                int r = m0 + mi * 16 + kg * 4 + i;
                int c = n0 + ni * 16 + c16;
                C[(size_t)r * 512 + c] = __float2bfloat16(acc[mi][ni][i] + bias[c]);
            }
}

// ---------------------------------------------------------------------------
// GACT partial: P[z][64][2560] = h @ [W_beta|W_dec]^T  over K-half z.
// No bias/activation here (done in attawe). grid (40, 4, 2).
// ---------------------------------------------------------------------------
__global__ __launch_bounds__(64) void gact_gemm(
    const __hip_bfloat16* __restrict__ H,   // xh+2560, lda 3072
    const __hip_bfloat16* __restrict__ Wb,  // [2048][512]
    const __hip_bfloat16* __restrict__ Wd,  // [512][512]
    float* __restrict__ P) {
    const int l = threadIdx.x, c16 = l & 15, kg = l >> 4;
    const int n0 = blockIdx.x * 64, m0 = blockIdx.y * 16, z = blockIdx.z;
    const int ko = z * 256;
    f4v acc[1][4];
#pragma unroll
    for (int ni = 0; ni < 4; ++ni) acc[0][ni] = (f4v)0.0f;
    const __hip_bfloat16* arow[1] = { H + (size_t)(m0 + c16) * 3072 + ko + kg * 8 };
    const __hip_bfloat16* wrow[4];
#pragma unroll
    for (int ni = 0; ni < 4; ++ni) {
        int n = n0 + ni * 16 + c16;
        wrow[ni] = ((n < 2048) ? Wb + (size_t)n * 512 : Wd + (size_t)(n - 2048) * 512) + ko + kg * 8;
    }
    gemm_seg<1, 8>(arow, wrow, acc);
    float* Pz = P + (size_t)z * (64 * 2560);
#pragma unroll
    for (int ni = 0; ni < 4; ++ni)
#pragma unroll
        for (int i = 0; i < 4; ++i) {
            int r = m0 + kg * 4 + i;
            int c = n0 + ni * 16 + c16;
            Pz[(size_t)r * 2560 + c] = acc[0][ni][i];
        }
}

// ---------------------------------------------------------------------------
// GATES partial: P[z][64][2048]; z=0: k[0,1536) W_ih; z=1: k[1536,2560) W_ih
// + k[2560,3072)->W_hh[0,512). grid (32, 4, 2). Bias added in cell.
// ---------------------------------------------------------------------------
__global__ __launch_bounds__(64) void gates_gemm(
    const __hip_bfloat16* __restrict__ X,    // xh, lda 3072
    const __hip_bfloat16* __restrict__ Wih,  // [2048][2560]
    const __hip_bfloat16* __restrict__ Whh,  // [2048][512]
    float* __restrict__ P) {
    const int l = threadIdx.x, c16 = l & 15, kg = l >> 4;
    const int n0 = blockIdx.x * 64, m0 = blockIdx.y * 16, z = blockIdx.z;
    f4v acc[1][4];
#pragma unroll
    for (int ni = 0; ni < 4; ++ni) acc[0][ni] = (f4v)0.0f;
    const __hip_bfloat16* arow[1];
    const __hip_bfloat16* wrow[4];
    if (z == 0) {
        arow[0] = X + (size_t)(m0 + c16) * 3072 + kg * 8;
#pragma unroll
        for (int ni = 0; ni < 4; ++ni)
            wrow[ni] = Wih + (size_t)(n0 + ni * 16 + c16) * 2560 + kg * 8;
        gemm_seg<1, 48>(arow, wrow, acc);
    } else {
        arow[0] = X + (size_t)(m0 + c16) * 3072 + 1536 + kg * 8;
#pragma unroll
        for (int ni = 0; ni < 4; ++ni)
            wrow[ni] = Wih + (size_t)(n0 + ni * 16 + c16) * 2560 + 1536 + kg * 8;
        gemm_seg<1, 32>(arow, wrow, acc);
        arow[0] = X + (size_t)(m0 + c16) * 3072 + 2560 + kg * 8;
#pragma unroll
        for (int ni = 0; ni < 4; ++ni)
            wrow[ni] = Whh + (size_t)(n0 + ni * 16 + c16) * 512 + kg * 8;
        gemm_seg<1, 16>(arow, wrow, acc);
    }
    float* Pz = P + (size_t)z * (64 * 2048);
#pragma unroll
    for (int ni = 0; ni < 4; ++ni)
#pragma unroll
        for (int i = 0; i < 4; ++i) {
            int r = m0 + kg * 4 + i;
            int c = n0 + ni * 16 + c16;
            Pz[(size_t)r * 2048 + c] = acc[0][ni][i];
        }
}

// ---------------------------------------------------------------------------
// Batched preds (all timesteps): out = hstore @ W_fc^T + b_fc, masked.
// hstore rows r = t*64 + b. M=1856, N=10000 (grid padded to 160 n-tiles).
// grid (160, 58): same-n blocks co-locate per XCD (weights shared).
// ---------------------------------------------------------------------------
__global__ __launch_bounds__(64) void predsb_gemm(
    const __hip_bfloat16* __restrict__ Hs,   // [1856][512]
    const __hip_bfloat16* __restrict__ Wfc,  // [10000][512]
    const float* __restrict__ bias,
    const int* __restrict__ dec_lens,
    float* __restrict__ out) {
    const int l = threadIdx.x, c16 = l & 15, kg = l >> 4;
    const int n0 = blockIdx.x * 64, m0 = blockIdx.y * 32;
    f4v acc[2][4];
#pragma unroll
    for (int mi = 0; mi < 2; ++mi)
#pragma unroll
        for (int ni = 0; ni < 4; ++ni) acc[mi][ni] = (f4v)0.0f;
    const __hip_bfloat16* arow[2];
#pragma unroll
    for (int mi = 0; mi < 2; ++mi)
        arow[mi] = Hs + (size_t)(m0 + mi * 16 + c16) * 512 + kg * 8;
    const __hip_bfloat16* wrow[4];
#pragma unroll
    for (int ni = 0; ni < 4; ++ni) {
        int n = n0 + ni * 16 + c16;
        int nn = (n < VOC) ? n : (VOC - 1);
        wrow[ni] = Wfc + (size_t)nn * 512 + kg * 8;
    }
    gemm_seg<2, 16>(arow, wrow, acc);
#pragma unroll
    for (int mi = 0; mi < 2; ++mi)
#pragma unroll
        for (int ni = 0; ni < 4; ++ni)
#pragma unroll
            for (int i = 0; i < 4; ++i) {
                int r = m0 + mi * 16 + kg * 4 + i;
                int c = n0 + ni * 16 + c16;
                if (c < VOC) {
                    int tt = r >> 6, b = r & 63;
                    float v = acc[mi][ni][i] + bias[c];
                    out[(size_t)b * (TSTEPS * VOC) + (size_t)tt * VOC + c] =
                        (tt < dec_lens[b]) ? v : 0.f;
                }
            }
}

// ---------------------------------------------------------------------------
// Fused attention: sums GACT partials (+bias, sigmoid for gate), e-scores ->
// softmax -> gated awe + emb gather into xh. One block per b.
// ---------------------------------------------------------------------------
__global__ __launch_bounds__(256) void attawe_kernel(
    const __hip_bfloat16* __restrict__ att1, const float* __restrict__ gactp,
    const __hip_bfloat16* __restrict__ enc_s,
    const float* __restrict__ w_full, const float* __restrict__ b_full,
    const float* __restrict__ b_dec, const float* __restrict__ b_beta,
    const float* __restrict__ emb_table,
    const int* __restrict__ caps_s, const int* __restrict__ dec_lens,
    __hip_bfloat16* __restrict__ xh, float* __restrict__ out_alphas, int t) {
    const int G = 64 * 2560;
    int b = blockIdx.x;
    int tid = threadIdx.x;
    __shared__ float s_att2[ATTD];
    __shared__ float s_wf[ATTD];
    __shared__ float s_e[PDIM];
    __shared__ float red[256];

    const float* gb = gactp + (size_t)b * 2560;
    s_att2[tid]       = gb[2048 + tid]       + gb[G + 2048 + tid]       + b_dec[tid];
    s_att2[tid + 256] = gb[2048 + 256 + tid] + gb[G + 2048 + 256 + tid] + b_dec[256 + tid];
    s_wf[tid]       = w_full[tid];
    s_wf[tid + 256] = w_full[tid + 256];
    __syncthreads();

    // --- e-scores ---
    int wv = tid >> 6, lane = tid & 63;
    const float bf = b_full[0];
    const int a0 = lane << 3;
    for (int p = wv; p < PDIM; p += 4) {
        const ushort* row = (const ushort*)att1 + ((size_t)b * PDIM + p) * ATTD + a0;
        float s = 0.f;
#pragma unroll
        for (int i = 0; i < 8; ++i) {
            float x = bf2f(row[i]) + s_att2[a0 + i];
            s += fmaxf(x, 0.f) * s_wf[a0 + i];
        }
#pragma unroll
        for (int off = 32; off; off >>= 1) s += __shfl_xor(s, off);
        if (lane == 0) s_e[p] = s + bf;
    }
    __syncthreads();

    // --- softmax (alpha stays in s_e) ---
    float v = (tid < PDIM) ? s_e[tid] : -FLT_MAX;
    red[tid] = v;
    __syncthreads();
    for (int st = 128; st; st >>= 1) {
        if (tid < st) red[tid] = fmaxf(red[tid], red[tid + st]);
        __syncthreads();
    }
    float mx = red[0];
    __syncthreads();
    float ex = (tid < PDIM) ? expf(v - mx) : 0.f;
    red[tid] = ex;
    __syncthreads();
    for (int st = 128; st; st >>= 1) {
        if (tid < st) red[tid] += red[tid + st];
        __syncthreads();
    }
    float inv = 1.f / red[0];
    __syncthreads();
    if (tid < PDIM) {
        float al = ex * inv;
        s_e[tid] = al;
        out_alphas[(size_t)b * (TSTEPS * PDIM) + (size_t)t * PDIM + tid] =
            (t < dec_lens[b]) ? al : 0.f;
    }
    __syncthreads();

    // --- awe: thread owns 8 consecutive e's (16B bf16 loads) ---
    int e = tid << 3;
    const ushort* ep = (const ushort*)enc_s + (size_t)b * (PDIM * ENC) + e;
    float acc[8];
#pragma unroll
    for (int i = 0; i < 8; ++i) acc[i] = 0.f;
#pragma unroll 2
    for (int p = 0; p < PDIM; ++p) {
        float al = s_e[p];
        s8v u = *(const s8v*)(ep + (size_t)p * ENC);
#pragma unroll
        for (int i = 0; i < 8; ++i) acc[i] += al * bf2f((ushort)u[i]);
    }
    float4 p00 = *(const float4*)(gb + e);
    float4 p01 = *(const float4*)(gb + e + 4);
    float4 p10 = *(const float4*)(gb + G + e);
    float4 p11 = *(const float4*)(gb + G + e + 4);
    float4 bb0 = *(const float4*)(b_beta + e);
    float4 bb1 = *(const float4*)(b_beta + e + 4);
    float g[8];
    g[0] = sigf(p00.x + p10.x + bb0.x); g[1] = sigf(p00.y + p10.y + bb0.y);
    g[2] = sigf(p00.z + p10.z + bb0.z); g[3] = sigf(p00.w + p10.w + bb0.w);
    g[4] = sigf(p01.x + p11.x + bb1.x); g[5] = sigf(p01.y + p11.y + bb1.y);
    g[6] = sigf(p01.z + p11.z + bb1.z); g[7] = sigf(p01.w + p11.w + bb1.w);
    __hip_bfloat16 ob[8];
#pragma unroll
    for (int i = 0; i < 8; ++i) ob[i] = __float2bfloat16(acc[i] * g[i]);
    *(uint4*)(xh + (size_t)b * 3072 + 512 + e) = *(uint4*)ob;

    // --- embedding gather ---
    if (tid < 128) {
        int cap = caps_s[b * LCAP + t];
        int j = tid << 2;
        float4 em = *(const float4*)(emb_table + (size_t)cap * EMBD + j);
        __hip_bfloat16 eb[4];
        eb[0] = __float2bfloat16(em.x); eb[1] = __float2bfloat16(em.y);
        eb[2] = __float2bfloat16(em.z); eb[3] = __float2bfloat16(em.w);
        *(uint2*)(xh + (size_t)b * 3072 + j) = *(uint2*)eb;
    }
}

// ---------------------------------------------------------------------------
// LSTM cell: sum GATES partials + biases, update c (fp32), write h (bf16)
// into xh h-slot AND hstore[t].
// ---------------------------------------------------------------------------
__global__ __launch_bounds__(256) void cell_kernel(
    const float* __restrict__ gatesp, const float* __restrict__ b_ih,
    const float* __restrict__ b_hh, float* __restrict__ c,
    __hip_bfloat16* __restrict__ xh, __hip_bfloat16* __restrict__ hstore, int t) {
    const int GS = 64 * 2048;
    int idx = blockIdx.x * 256 + threadIdx.x;  // < 64*512
    int b = idx >> 9, j = idx & 511;
    const float* g0 = gatesp + (size_t)b * 2048;
    const float* g1 = gatesp + GS + (size_t)b * 2048;
    float vi = g0[j]        + g1[j]        + b_ih[j]        + b_hh[j];
    float vf = g0[512 + j]  + g1[512 + j]  + b_ih[512 + j]  + b_hh[512 + j];
    float vg = g0[1024 + j] + g1[1024 + j] + b_ih[1024 + j] + b_hh[1024 + j];
    float vo = g0[1536 + j] + g1[1536 + j] + b_ih[1536 + j] + b_hh[1536 + j];
    float i_ = sigf(vi), f_ = sigf(vf), gg = tanhf(vg), o_ = sigf(vo);
    float cn = f_ * c[idx] + i_ * gg;
    c[idx] = cn;
    __hip_bfloat16 hb = __float2bfloat16(o_ * tanhf(cn));
    xh[(size_t)b * 3072 + 2560 + j] = hb;
    hstore[(size_t)t * (64 * 512) + idx] = hb;
}

// ---------------------------------------------------------------------------
extern "C" void kernel_launch(void* const* d_in, const int* in_sizes, int n_in,
                              void* d_out, int out_size, void* d_ws, size_t ws_size,
                              hipStream_t stream) {
    const float* enc      = (const float*)d_in[0];
    const int*   caps     = (const int*)d_in[1];
    const int*   clen     = (const int*)d_in[2];
    const float* W_enc    = (const float*)d_in[3];
    const float* b_enc    = (const float*)d_in[4];
    const float* W_dec    = (const float*)d_in[5];
    const float* b_dec    = (const float*)d_in[6];
    const float* w_full   = (const float*)d_in[7];
    const float* b_full   = (const float*)d_in[8];
    const float* emb_tab  = (const float*)d_in[9];
    const float* W_ih     = (const float*)d_in[10];
    const float* b_ih     = (const float*)d_in[11];
    const float* W_hh     = (const float*)d_in[12];
    const float* b_hh     = (const float*)d_in[13];
    const float* W_init_h = (const float*)d_in[14];
    const float* b_init_h = (const float*)d_in[15];
    const float* W_init_c = (const float*)d_in[16];
    const float* b_init_c = (const float*)d_in[17];
    const float* W_beta   = (const float*)d_in[18];
    const float* b_beta   = (const float*)d_in[19];
    const float* W_fc     = (const float*)d_in[20];
    const float* b_fc     = (const float*)d_in[21];

    float* out_pred = (float*)d_out;
    float* out_alph = out_pred + (size_t)BDIM * TSTEPS * VOC;
    float* out_caps = out_alph + (size_t)BDIM * TSTEPS * PDIM;
    float* out_dlen = out_caps + BDIM * LCAP;
    float* out_sind = out_dlen + BDIM;

    // ---- workspace carve-up (256B aligned) ----
    char* p = (char*)d_ws;
    auto carve = [&](size_t bytes) { char* r = p; p += (bytes + 255) & ~(size_t)255; return r; };
    int* sort_ind = (int*)carve(64 * 4);
    int* dec_lens = (int*)carve(64 * 4);
    int* caps_s   = (int*)carve(64 * LCAP * 4);
    float* mean_e = (float*)carve((size_t)64 * ENC * 4);
    float* h0f    = (float*)carve((size_t)64 * 512 * 4);
    float* cbuf   = (float*)carve((size_t)64 * 512 * 4);
    float* gactp  = (float*)carve((size_t)2 * 64 * 2560 * 4);
    float* gatesp = (float*)carve((size_t)2 * 64 * 2048 * 4);
    __hip_bfloat16* xh     = (__hip_bfloat16*)carve((size_t)64 * 3072 * 2);
    __hip_bfloat16* hstore = (__hip_bfloat16*)carve((size_t)TSTEPS * 64 * 512 * 2);
    __hip_bfloat16* enc_s  = (__hip_bfloat16*)carve((size_t)64 * PDIM * ENC * 2);
    __hip_bfloat16* att1   = (__hip_bfloat16*)carve((size_t)64 * PDIM * 512 * 2);
    __hip_bfloat16* Wb_enc = (__hip_bfloat16*)carve((size_t)512 * 2048 * 2);
    __hip_bfloat16* Wb_bet = (__hip_bfloat16*)carve((size_t)2048 * 512 * 2);
    __hip_bfloat16* Wb_dec = (__hip_bfloat16*)carve((size_t)512 * 512 * 2);
    __hip_bfloat16* Wb_ih  = (__hip_bfloat16*)carve((size_t)2048 * 2560 * 2);
    __hip_bfloat16* Wb_hh  = (__hip_bfloat16*)carve((size_t)2048 * 512 * 2);
    __hip_bfloat16* Wb_fc  = (__hip_bfloat16*)carve((size_t)VOC * 512 * 2);

    // ---- init phase ----
    sort_kernel<<<1, 64, 0, stream>>>(clen, caps, sort_ind, dec_lens, caps_s,
                                      out_caps, out_dlen, out_sind);
    conv_enc_kernel<<<dim3(8, 64), 256, 0, stream>>>(enc, sort_ind, enc_s, mean_e);
    f2b_kernel<<<(512 * 2048 + 255) / 256, 256, 0, stream>>>(W_enc, Wb_enc, 512 * 2048);
    f2b_kernel<<<(2048 * 512 + 255) / 256, 256, 0, stream>>>(W_beta, Wb_bet, 2048 * 512);
    f2b_kernel<<<(512 * 512 + 255) / 256, 256, 0, stream>>>(W_dec, Wb_dec, 512 * 512);
    f2b_kernel<<<(2048 * 2560 + 255) / 256, 256, 0, stream>>>(W_ih, Wb_ih, 2048 * 2560);
    f2b_kernel<<<(2048 * 512 + 255) / 256, 256, 0, stream>>>(W_hh, Wb_hh, 2048 * 512);
    f2b_kernel<<<(VOC * 512 + 255) / 256, 256, 0, stream>>>(W_fc, Wb_fc, VOC * 512);

    gemm32_k<<<dim3(8, 1), 256, 0, stream>>>(mean_e, ENC, W_init_h, b_init_h, h0f, 512, ENC);
    gemm32_k<<<dim3(8, 1), 256, 0, stream>>>(mean_e, ENC, W_init_c, b_init_c, cbuf, 512, ENC);
    h0_kernel<<<128, 256, 0, stream>>>(h0f, xh);

    // att1 (M=12544, N=512, K=2048) -> bf16
    att1_gemm<<<dim3(392, 8), 64, 0, stream>>>(enc_s, Wb_enc, b_enc, att1);

    // ---- decode loop ----
    for (int t = 0; t < TSTEPS; ++t) {
        gact_gemm<<<dim3(40, 4, 2), 64, 0, stream>>>(xh + 2560, Wb_bet, Wb_dec, gactp);
        attawe_kernel<<<64, 256, 0, stream>>>(att1, gactp, enc_s, w_full, b_full,
                                              b_dec, b_beta, emb_tab, caps_s,
                                              dec_lens, xh, out_alph, t);
        gates_gemm<<<dim3(32, 4, 2), 64, 0, stream>>>(xh, Wb_ih, Wb_hh, gatesp);
        cell_kernel<<<128, 256, 0, stream>>>(gatesp, b_ih, b_hh, cbuf, xh, hstore, t);
    }

    // batched preds over all timesteps (M=29*64=1856, N=10000, K=512)
    predsb_gemm<<<dim3(160, 58), 64, 0, stream>>>(hstore, Wb_fc, b_fc, dec_lens, out_pred);
}